// Round 3
// baseline (977.758 us; speedup 1.0000x reference)
//
#include <hip/hip_runtime.h>

// ---------------- problem constants ----------------
#define E_EDGES 64800
#define NC      842
#define NB      8          // b*t = 2*4
#define FIN     78
#define E_LAT   5894
#define NROWS_NODE (NB*NC)   // 6736
#define NTILES_E 1013        // ceil(64800/64)

// output layout (flat float32)
#define OUT_IDX_OFF   1724416
#define OUT_IDX_N     11788
#define OUT_ATTR_OFF  1736204

// workspace layout (bytes)
#define AGG_OFF    0
#define CNT_OFF    6897664
#define CUR_OFF    6901032
#define PERM_OFF   6904400
#define WPACK_OFF  7163904

// packed-weight element offsets (bf16 elements)
#define WOFF_E0 0
#define WOFF_E1 40960
#define WOFF_E2 106496
#define WOFF_N0 172032
#define WOFF_N1 262144
#define WOFF_N2 327680
#define WOFF_R0 393216
#define WOFF_R1 401408
#define WOFF_R2 466944

// LDS strides (bf16 elems). For b128 A-frag reads, start bank = S_dw*m15 + 4q
// (mod 32); S_dw ≡ 3 or 5 (mod 8) keeps bank groups ≤~2-way (free per m136).
// SA_E=166 -> 83 dw (83%8=3); SH=262 -> 131 dw (131%8=3); SA_N=362 -> 181 dw
// (181%8=5); SA_R=42 -> 21 dw (21%8=5).
#define SA_E 166
#define SH   262
#define SA_N 362
#define SA_R 42

typedef __bf16 bf16x8 __attribute__((ext_vector_type(8)));
typedef float  f32x4  __attribute__((ext_vector_type(4)));

__device__ __forceinline__ unsigned short f2bf(float f) {
    unsigned u = __builtin_bit_cast(unsigned, f);
    return (unsigned short)((u + 0x7fffu + ((u >> 16) & 1u)) >> 16);  // RNE
}
__device__ __forceinline__ unsigned packbf2(float lo, float hi) {
    return (unsigned)f2bf(lo) | ((unsigned)f2bf(hi) << 16);
}
__device__ __forceinline__ float leakyf(float v) { return v > 0.f ? v : 0.01f * v; }

template<int MF>
__device__ __forceinline__ void zero_acc(f32x4 (&acc)[MF][4]) {
#pragma unroll
    for (int mf = 0; mf < MF; ++mf)
#pragma unroll
        for (int nf = 0; nf < 4; ++nf)
            acc[mf][nf] = (f32x4){0.f, 0.f, 0.f, 0.f};
}

// C[MF*16 rows x 64-col wave slice] += A_lds * Wpacked.  Full unroll (NKS is
// compile-time) + explicit B-fragment prefetch so global weight loads pipeline
// ahead of the MFMAs instead of serializing per (kk,nf).
template<int MF, int NKS>
__device__ __forceinline__ void run_layer(const unsigned short* lA, int strideA,
                                          const unsigned short* Wp, int nfg0,
                                          int m15, int q, int lane, f32x4 (&acc)[MF][4]) {
    const unsigned short* wp0 = Wp + (size_t)nfg0 * 512 + lane * 8;
    bf16x8 bcur[4], bnxt[4];
#pragma unroll
    for (int nf = 0; nf < 4; ++nf) bcur[nf] = *(const bf16x8*)(wp0 + nf * 512);
#pragma unroll
    for (int kk = 0; kk < NKS; ++kk) {
        if (kk + 1 < NKS) {
#pragma unroll
            for (int nf = 0; nf < 4; ++nf)
                bnxt[nf] = *(const bf16x8*)(wp0 + (size_t)(kk + 1) * 16 * 512 + nf * 512);
        }
        bf16x8 a[MF];
#pragma unroll
        for (int mf = 0; mf < MF; ++mf)
            a[mf] = *(const bf16x8*)(lA + (mf * 16 + m15) * strideA + kk * 32 + q * 8);
#pragma unroll
        for (int nf = 0; nf < 4; ++nf)
#pragma unroll
            for (int mf = 0; mf < MF; ++mf)
                acc[mf][nf] = __builtin_amdgcn_mfma_f32_16x16x32_bf16(a[mf], bcur[nf], acc[mf][nf], 0, 0, 0);
#pragma unroll
        for (int nf = 0; nf < 4; ++nf) bcur[nf] = bnxt[nf];
    }
}

// H[row*SH+col] = bf16(leaky(acc + bias[col]))
template<int MF>
__device__ __forceinline__ void epi_to_H(unsigned short* Hb, const f32x4 (&acc)[MF][4],
                                         const float* bias, int w, int m15, int q) {
#pragma unroll
    for (int nf = 0; nf < 4; ++nf) {
        int col = w * 64 + nf * 16 + m15;
        float bv = bias[col];
#pragma unroll
        for (int mf = 0; mf < MF; ++mf)
#pragma unroll
            for (int r4 = 0; r4 < 4; ++r4) {
                int row = mf * 16 + q * 4 + r4;
                Hb[row * SH + col] = f2bf(leakyf(acc[mf][nf][r4] + bv));
            }
    }
}

// ---------------- weight packing ----------------
__global__ void pack_weights(const float* s0, const float* s1, const float* s2,
                             const float* s3, const float* s4, const float* s5,
                             const float* s6, const float* s7, const float* s8,
                             unsigned short* wp) {
    const int ksA[9]  = {5, 8, 8, 11, 8, 8, 1, 8, 8};
    const int kaA[9]  = {158, 256, 256, 334, 256, 256, 2, 256, 256};
    const int offA[9] = {WOFF_E0, WOFF_E1, WOFF_E2, WOFF_N0, WOFF_N1, WOFF_N2,
                         WOFF_R0, WOFF_R1, WOFF_R2};
    const float* srcs[9] = {s0, s1, s2, s3, s4, s5, s6, s7, s8};
    int rem = blockIdx.x;
    int l = 0;
    while (rem >= ksA[l] * 16) { rem -= ksA[l] * 16; ++l; }
    int kk = rem >> 4, nf = rem & 15;
    int lane = threadIdx.x >> 3, j = threadIdx.x & 7;
    int k = kk * 32 + (lane >> 4) * 8 + j;
    int n = nf * 16 + (lane & 15);
    float v = (k < kaA[l]) ? srcs[l][k * 256 + n] : 0.f;
    wp[(size_t)offA[l] + (size_t)(kk * 16 + nf) * 512 + lane * 8 + j] = f2bf(v);
}

// ---------------- counting sort of edges by dst ----------------
__global__ void hist_kernel(const int* __restrict__ dstA, int* __restrict__ cnt) {
    int e = blockIdx.x * 256 + threadIdx.x;
    if (e < E_EDGES) atomicAdd(&cnt[dstA[e]], 1);
}
__global__ void scan_kernel(const int* __restrict__ cnt, int* __restrict__ cursor) {
    __shared__ int s[1024];
    int t = threadIdx.x;
    s[t] = (t < NC) ? cnt[t] : 0;
    __syncthreads();
    for (int d = 1; d < 1024; d <<= 1) {
        int v = (t >= d) ? s[t - d] : 0;
        __syncthreads();
        s[t] += v;
        __syncthreads();
    }
    if (t < NC) cursor[t] = (t == 0) ? 0 : s[t - 1];
}
__global__ void scatter_kernel(const int* __restrict__ dstA, int* __restrict__ cursor,
                               int* __restrict__ perm) {
    int e = blockIdx.x * 256 + threadIdx.x;
    if (e < E_EDGES) {
        int p = atomicAdd(&cursor[dstA[e]], 1);
        perm[p] = e;
    }
}

// ------- fused 3-layer edge MLP (single batch/block) + in-register segment reduce ----
__global__ __launch_bounds__(256, 2) void edge_mlp_kernel(
    const float* __restrict__ x, const int* __restrict__ edge_index,
    const float* __restrict__ eattr, const float* __restrict__ h3,
    const float* __restrict__ eb0, const float* __restrict__ eb1, const float* __restrict__ eb2,
    const unsigned short* __restrict__ wpack, const int* __restrict__ perm,
    float* __restrict__ agg) {
    const int* srcA = edge_index;
    const int* dstA = edge_index + E_EDGES;
    __shared__ __align__(16) unsigned short As[64 * SA_E];   // [x(78)|h3(78)|attr(2)|pad]
    __shared__ __align__(16) unsigned short Hs[64 * SH];
    __shared__ short dstl[64];
    __shared__ int eidl[64];
    __shared__ unsigned short srcl[64];
    __shared__ unsigned char starts[68];
    __shared__ int nseg;

    const int base = blockIdx.x * 64, b = blockIdx.y;
    const int tid = threadIdx.x, lane = tid & 63, w = tid >> 6;
    const int m15 = lane & 15, q = lane >> 4;

    if (tid < 64) {
        int eg = base + tid;
        int e = (eg < E_EDGES) ? perm[eg] : -1;
        eidl[tid] = e;
        dstl[tid] = (e >= 0) ? (short)dstA[e] : (short)-1;
        srcl[tid] = (e >= 0) ? (unsigned short)srcA[e] : 0;
    }
    if (tid == 65) nseg = -1;   // placeholder touch to keep shape
    __syncthreads();

    // segment starts (once per block)
    if (tid == 0) {
        int ns = 0; short prev = -2; int r = 0;
        for (; r < 64; ++r) {
            short d = dstl[r];
            if (d < 0) break;
            if (d != prev) { starts[ns++] = (unsigned char)r; prev = d; }
        }
        starts[ns] = (unsigned char)r;
        nseg = ns;
    }

    // stage layer-0 input tile, 4 lanes per row, float2 -> packed bf16
    {
        const int rr = tid >> 2, j = tid & 3;
        const int d = dstl[rr];
        const int valid = (d >= 0);
        const float* xr = x + ((size_t)b * E_EDGES + srcl[rr]) * FIN;
        // x part: cols 0..77
        for (int p = j; p < 39; p += 4) {
            unsigned pv = 0;
            if (valid) { float2 f = *(const float2*)(xr + 2 * p); pv = packbf2(f.x, f.y); }
            *(unsigned*)(As + rr * SA_E + 2 * p) = pv;
        }
        // h3 (78..155), attr (156..157), zero pad (158..165)
        const float* hr = h3 + (valid ? d : 0) * FIN;
        for (int p = j; p < 44; p += 4) {
            unsigned pv = 0;
            if (valid) {
                if (p < 39) { float2 f = *(const float2*)(hr + 2 * p); pv = packbf2(f.x, f.y); }
                else if (p == 39) { float2 f = *(const float2*)(eattr + (size_t)eidl[rr] * 2); pv = packbf2(f.x, f.y); }
            }
            *(unsigned*)(As + rr * SA_E + 78 + 2 * p) = pv;
        }
    }
    float bnf[4];
#pragma unroll
    for (int nf = 0; nf < 4; ++nf) bnf[nf] = eb2[w * 64 + nf * 16 + m15];
    __syncthreads();

    f32x4 acc[4][4];
    zero_acc<4>(acc);
    run_layer<4, 5>(As, SA_E, wpack + WOFF_E0, w * 4, m15, q, lane, acc);   // K=160
    epi_to_H<4>(Hs, acc, eb0, w, m15, q);
    __syncthreads();

    zero_acc<4>(acc);
    run_layer<4, 8>(Hs, SH, wpack + WOFF_E1, w * 4, m15, q, lane, acc);     // K=256
    __syncthreads();
    epi_to_H<4>(Hs, acc, eb1, w, m15, q);
    __syncthreads();

    zero_acc<4>(acc);
    run_layer<4, 8>(Hs, SH, wpack + WOFF_E2, w * 4, m15, q, lane, acc);     // K=256

    // ---- per-nf in-register segment reduce + predicated atomic flush ----
    const int ns = nseg;
#pragma unroll
    for (int nf = 0; nf < 4; ++nf) {
        for (int s = 0; s < ns; ++s) {
            const int lo = starts[s], hi = starts[s + 1];
            float t = 0.f;
#pragma unroll
            for (int mf = 0; mf < 4; ++mf)
#pragma unroll
                for (int r4 = 0; r4 < 4; ++r4) {
                    int row = mf * 16 + q * 4 + r4;
                    t += (row >= lo && row < hi) ? acc[mf][nf][r4] : 0.f;
                }
            t += __shfl_xor(t, 16, 64);
            t += __shfl_xor(t, 32, 64);
            if (q == nf) {
                int dc = dstl[lo];
                atomicAdd(&agg[((size_t)b * NC + dc) * 256 + w * 64 + nf * 16 + m15],
                          t + bnf[nf] * (float)(hi - lo));
            }
        }
    }
}

// ---------------- node MLP (32-row tiles) ----------------
__global__ __launch_bounds__(256, 2) void node_mlp_kernel(
    const float* __restrict__ h3, const float* __restrict__ agg,
    const float* __restrict__ nb0, const float* __restrict__ nb1, const float* __restrict__ nb2,
    const unsigned short* __restrict__ wpack, float* __restrict__ out) {
    __shared__ __align__(16) unsigned short As[32 * SA_N];
    __shared__ __align__(16) unsigned short Hs[32 * SH];
    __shared__ int cl[32], vl[32];

    const int base = blockIdx.x * 32;
    const int tid = threadIdx.x, lane = tid & 63, w = tid >> 6;
    const int m15 = lane & 15, q = lane >> 4;

    if (tid < 32) {
        int jj = base + tid;
        vl[tid] = (jj < NROWS_NODE);
        cl[tid] = vl[tid] ? (jj % NC) : 0;
    }
    __syncthreads();

    for (int i = tid; i < 32 * 352; i += 256) {
        int r = i / 352, k = i - r * 352;
        float v = 0.f;
        if (vl[r]) {
            int jj = base + r;
            if (k < 78) v = h3[cl[r] * FIN + k];
            else if (k < 334) v = agg[(size_t)jj * 256 + (k - 78)];
        }
        As[r * SA_N + k] = f2bf(v);
    }
    __syncthreads();

    f32x4 acc[2][4];
    zero_acc<2>(acc);
    run_layer<2, 11>(As, SA_N, wpack + WOFF_N0, w * 4, m15, q, lane, acc);   // K=352
    epi_to_H<2>(Hs, acc, nb0, w, m15, q);
    __syncthreads();

    zero_acc<2>(acc);
    run_layer<2, 8>(Hs, SH, wpack + WOFF_N1, w * 4, m15, q, lane, acc);
    __syncthreads();
    epi_to_H<2>(Hs, acc, nb1, w, m15, q);
    __syncthreads();

    zero_acc<2>(acc);
    run_layer<2, 8>(Hs, SH, wpack + WOFF_N2, w * 4, m15, q, lane, acc);

#pragma unroll
    for (int nf = 0; nf < 4; ++nf) {
        int col = w * 64 + nf * 16 + m15;
        float bv = nb2[col];
#pragma unroll
        for (int mf = 0; mf < 2; ++mf)
#pragma unroll
            for (int r4 = 0; r4 < 4; ++r4) {
                int row = mf * 16 + q * 4 + r4;
                int jj = base + row;
                if (jj < NROWS_NODE) out[(size_t)jj * 256 + col] = acc[mf][nf][r4] + bv;
            }
    }
}

// ---------------- residual MLP (32-row tiles) ----------------
__global__ __launch_bounds__(256, 2) void res_mlp_kernel(
    const float* __restrict__ la, const float* __restrict__ rb0, const float* __restrict__ rb1,
    const float* __restrict__ rb2, const float* __restrict__ rWs, const float* __restrict__ rbs,
    const unsigned short* __restrict__ wpack, float* __restrict__ out) {
    __shared__ __align__(16) unsigned short As[32 * SA_R];
    __shared__ __align__(16) unsigned short Hs[32 * SH];

    const int base = blockIdx.x * 32;
    const int tid = threadIdx.x, lane = tid & 63, w = tid >> 6;
    const int m15 = lane & 15, q = lane >> 4;

    for (int i = tid; i < 32 * SA_R; i += 256) {
        int r = i / SA_R, k = i - r * SA_R;
        int e = base + r;
        float v = (e < E_LAT && k < 2) ? la[e * 2 + k] : 0.f;
        As[i] = f2bf(v);
    }
    __syncthreads();

    f32x4 acc[2][4];
    zero_acc<2>(acc);
    run_layer<2, 1>(As, SA_R, wpack + WOFF_R0, w * 4, m15, q, lane, acc);   // K=32 (2 real)
    epi_to_H<2>(Hs, acc, rb0, w, m15, q);
    __syncthreads();

    zero_acc<2>(acc);
    run_layer<2, 8>(Hs, SH, wpack + WOFF_R1, w * 4, m15, q, lane, acc);
    __syncthreads();
    epi_to_H<2>(Hs, acc, rb1, w, m15, q);
    __syncthreads();

    zero_acc<2>(acc);
    run_layer<2, 8>(Hs, SH, wpack + WOFF_R2, w * 4, m15, q, lane, acc);

#pragma unroll
    for (int nf = 0; nf < 4; ++nf) {
        int col = w * 64 + nf * 16 + m15;
        float bv = rb2[col] + rbs[col];
        float ws0 = rWs[col], ws1 = rWs[256 + col];
#pragma unroll
        for (int mf = 0; mf < 2; ++mf)
#pragma unroll
            for (int r4 = 0; r4 < 4; ++r4) {
                int row = mf * 16 + q * 4 + r4;
                int e = base + row;
                if (e < E_LAT) {
                    float v = acc[mf][nf][r4] + bv + la[e * 2] * ws0 + la[e * 2 + 1] * ws1;
                    out[(size_t)e * 256 + col] = v;
                }
            }
    }
}

__global__ void idx_copy_kernel(const int* __restrict__ lei, float* __restrict__ out) {
    int i = blockIdx.x * 256 + threadIdx.x;
    if (i < OUT_IDX_N) out[i] = (float)lei[i];
}

// ---------------- launch ----------------
extern "C" void kernel_launch(void* const* d_in, const int* in_sizes, int n_in,
                              void* d_out, int out_size, void* d_ws, size_t ws_size,
                              hipStream_t stream) {
    const float* x      = (const float*)d_in[0];
    const int*   eidx   = (const int*)d_in[1];
    const float* eattr  = (const float*)d_in[2];
    const int*   lei    = (const int*)d_in[3];
    const float* la     = (const float*)d_in[4];
    const float* h3     = (const float*)d_in[5];
    const float* eW0 = (const float*)d_in[6],  *eb0 = (const float*)d_in[7];
    const float* eW1 = (const float*)d_in[8],  *eb1 = (const float*)d_in[9];
    const float* eW2 = (const float*)d_in[10], *eb2 = (const float*)d_in[11];
    const float* nW0 = (const float*)d_in[12], *nb0 = (const float*)d_in[13];
    const float* nW1 = (const float*)d_in[14], *nb1 = (const float*)d_in[15];
    const float* nW2 = (const float*)d_in[16], *nb2 = (const float*)d_in[17];
    const float* rW0 = (const float*)d_in[18], *rb0 = (const float*)d_in[19];
    const float* rW1 = (const float*)d_in[20], *rb1 = (const float*)d_in[21];
    const float* rW2 = (const float*)d_in[22], *rb2 = (const float*)d_in[23];
    const float* rWs = (const float*)d_in[24], *rbs = (const float*)d_in[25];

    char* ws = (char*)d_ws;
    float* agg  = (float*)(ws + AGG_OFF);
    int* cnt    = (int*)(ws + CNT_OFF);
    int* cur    = (int*)(ws + CUR_OFF);
    int* perm   = (int*)(ws + PERM_OFF);
    unsigned short* wpack = (unsigned short*)(ws + WPACK_OFF);

    float* out = (float*)d_out;

    hipMemsetAsync(d_ws, 0, CUR_OFF, stream);   // agg + histogram counters

    pack_weights<<<1040, 512, 0, stream>>>(eW0, eW1, eW2, nW0, nW1, nW2, rW0, rW1, rW2, wpack);
    hist_kernel<<<254, 256, 0, stream>>>(eidx + E_EDGES, cnt);
    scan_kernel<<<1, 1024, 0, stream>>>(cnt, cur);
    scatter_kernel<<<254, 256, 0, stream>>>(eidx + E_EDGES, cur, perm);

    edge_mlp_kernel<<<dim3(NTILES_E, NB), 256, 0, stream>>>(x, eidx, eattr, h3,
                                                            eb0, eb1, eb2, wpack, perm, agg);
    node_mlp_kernel<<<211, 256, 0, stream>>>(h3, agg, nb0, nb1, nb2, wpack, out);
    res_mlp_kernel<<<185, 256, 0, stream>>>(la, rb0, rb1, rb2, rWs, rbs, wpack,
                                            out + OUT_ATTR_OFF);
    idx_copy_kernel<<<47, 256, 0, stream>>>(lei, out + OUT_IDX_OFF);
}

// Round 4
// 720.715 us; speedup vs baseline: 1.3566x; 1.3566x over previous
//
#include <hip/hip_runtime.h>

// ---------------- problem constants ----------------
#define E_EDGES 64800
#define NC      842
#define NB      8          // b*t = 2*4
#define FIN     78
#define E_LAT   5894
#define NROWS_NODE (NB*NC)   // 6736
#define NTILES_E 1013        // ceil(64800/64)

// output layout (flat float32)
#define OUT_IDX_OFF   1724416
#define OUT_IDX_N     11788
#define OUT_ATTR_OFF  1736204

// workspace layout (bytes)
#define AGG_OFF    0
#define CNT_OFF    6897664
#define CUR_OFF    6901032
#define SSRC_OFF   6904400
#define SDST_OFF   7163600
#define SATTR_OFF  7293200
#define WPACK_OFF  7811600

// packed-weight element offsets (bf16 elements)
#define WOFF_E0 0
#define WOFF_E1 40960
#define WOFF_E2 106496
#define WOFF_N0 172032
#define WOFF_N1 262144
#define WOFF_N2 327680
#define WOFF_R0 393216
#define WOFF_R1 401408
#define WOFF_R2 466944

// LDS strides (bf16 elems): dword stride ≡ 3 or 5 (mod 8) keeps b128 A-frag
// reads ≤2-way bank-aliased (free).  262 -> 131 dw (3 mod 8); 362 -> 181 dw (5 mod 8).
#define SH   262
#define SA_N 362

typedef __bf16 bf16x8 __attribute__((ext_vector_type(8)));
typedef float  f32x4  __attribute__((ext_vector_type(4)));

__device__ __forceinline__ unsigned short f2bf(float f) {   // RNE (pack_weights only)
    unsigned u = __builtin_bit_cast(unsigned, f);
    return (unsigned short)((u + 0x7fffu + ((u >> 16) & 1u)) >> 16);
}
// RTZ pack of two floats into two bf16 in one v_perm_b32
__device__ __forceinline__ unsigned packRTZ(float lo, float hi) {
    return __builtin_amdgcn_perm(__builtin_bit_cast(unsigned, hi),
                                 __builtin_bit_cast(unsigned, lo), 0x07060302u);
}

template<int MF>
__device__ __forceinline__ void zero_acc(f32x4 (&acc)[MF][4]) {
#pragma unroll
    for (int mf = 0; mf < MF; ++mf)
#pragma unroll
        for (int nf = 0; nf < 4; ++nf)
            acc[mf][nf] = (f32x4){0.f, 0.f, 0.f, 0.f};
}

// C[MF*16 rows x 64-col wave slice] += A_lds * Wpacked, B-fragment prefetch.
template<int MF, int NKS>
__device__ __forceinline__ void run_layer(const unsigned short* lA, int strideA,
                                          const unsigned short* Wp, int nfg0,
                                          int m15, int q, f32x4 (&acc)[MF][4]) {
    const unsigned short* wp0 = Wp + (size_t)nfg0 * 512 + (threadIdx.x & 63) * 8;
    bf16x8 bcur[4], bnxt[4];
#pragma unroll
    for (int nf = 0; nf < 4; ++nf) bcur[nf] = *(const bf16x8*)(wp0 + nf * 512);
#pragma unroll
    for (int kk = 0; kk < NKS; ++kk) {
        if (kk + 1 < NKS) {
#pragma unroll
            for (int nf = 0; nf < 4; ++nf)
                bnxt[nf] = *(const bf16x8*)(wp0 + (size_t)(kk + 1) * 16 * 512 + nf * 512);
        }
        bf16x8 a[MF];
#pragma unroll
        for (int mf = 0; mf < MF; ++mf)
            a[mf] = *(const bf16x8*)(lA + (mf * 16 + m15) * strideA + kk * 32 + q * 8);
#pragma unroll
        for (int nf = 0; nf < 4; ++nf)
#pragma unroll
            for (int mf = 0; mf < MF; ++mf)
                acc[mf][nf] = __builtin_amdgcn_mfma_f32_16x16x32_bf16(a[mf], bcur[nf], acc[mf][nf], 0, 0, 0);
#pragma unroll
        for (int nf = 0; nf < 4; ++nf) bcur[nf] = bnxt[nf];
    }
}

// S[row*stride+col] = bf16_rtz(leaky(acc + bias[col])); leaky = max(y, 0.01y)
template<int MF>
__device__ __forceinline__ void epi_act(unsigned short* Sb, int stride, const f32x4 (&acc)[MF][4],
                                        const float* bias, int w, int m15, int q) {
#pragma unroll
    for (int nf = 0; nf < 4; ++nf) {
        int col = w * 64 + nf * 16 + m15;
        float bv = bias[col];
#pragma unroll
        for (int mf = 0; mf < MF; ++mf)
#pragma unroll
            for (int r4 = 0; r4 < 4; ++r4) {
                int row = mf * 16 + q * 4 + r4;
                float y = acc[mf][nf][r4] + bv;
                y = fmaxf(y, 0.01f * y);
                Sb[row * stride + col] = (unsigned short)(__builtin_bit_cast(unsigned, y) >> 16);
            }
    }
}

// ---------------- weight packing ----------------
__global__ void pack_weights(const float* s0, const float* s1, const float* s2,
                             const float* s3, const float* s4, const float* s5,
                             const float* s6, const float* s7, const float* s8,
                             unsigned short* wp) {
    const int ksA[9]  = {5, 8, 8, 11, 8, 8, 1, 8, 8};
    const int kaA[9]  = {158, 256, 256, 334, 256, 256, 2, 256, 256};
    const int offA[9] = {WOFF_E0, WOFF_E1, WOFF_E2, WOFF_N0, WOFF_N1, WOFF_N2,
                         WOFF_R0, WOFF_R1, WOFF_R2};
    const float* srcs[9] = {s0, s1, s2, s3, s4, s5, s6, s7, s8};
    int rem = blockIdx.x;
    int l = 0;
    while (rem >= ksA[l] * 16) { rem -= ksA[l] * 16; ++l; }
    int kk = rem >> 4, nf = rem & 15;
    int lane = threadIdx.x >> 3, j = threadIdx.x & 7;
    int k = kk * 32 + (lane >> 4) * 8 + j;
    int n = nf * 16 + (lane & 15);
    float v = (k < kaA[l]) ? srcs[l][k * 256 + n] : 0.f;
    wp[(size_t)offA[l] + (size_t)(kk * 16 + nf) * 512 + lane * 8 + j] = f2bf(v);
}

// ---------------- counting sort of edges by dst (+ gather sorted meta) ----------------
__global__ void hist_kernel(const int* __restrict__ dstA, int* __restrict__ cnt) {
    int e = blockIdx.x * 256 + threadIdx.x;
    if (e < E_EDGES) atomicAdd(&cnt[dstA[e]], 1);
}
__global__ void scan_kernel(const int* __restrict__ cnt, int* __restrict__ cursor) {
    __shared__ int s[1024];
    int t = threadIdx.x;
    s[t] = (t < NC) ? cnt[t] : 0;
    __syncthreads();
    for (int d = 1; d < 1024; d <<= 1) {
        int v = (t >= d) ? s[t - d] : 0;
        __syncthreads();
        s[t] += v;
        __syncthreads();
    }
    if (t < NC) cursor[t] = (t == 0) ? 0 : s[t - 1];
}
__global__ void scatter_kernel(const int* __restrict__ srcA, const int* __restrict__ dstA,
                               const float* __restrict__ eattr, int* __restrict__ cursor,
                               int* __restrict__ ssrc, short* __restrict__ sdst,
                               float2* __restrict__ sattr) {
    int e = blockIdx.x * 256 + threadIdx.x;
    if (e < E_EDGES) {
        int d = dstA[e];
        int p = atomicAdd(&cursor[d], 1);
        ssrc[p] = srcA[e];
        sdst[p] = (short)d;
        sattr[p] = ((const float2*)eattr)[e];
    }
}

// ------- fused 3-layer edge MLP (overlay LDS, 4 blocks/CU) + in-reg segment reduce ----
__global__ __launch_bounds__(256, 4) void edge_mlp_kernel(
    const float* __restrict__ x, const float* __restrict__ h3,
    const float* __restrict__ eb0, const float* __restrict__ eb1, const float* __restrict__ eb2,
    const unsigned short* __restrict__ wpack, const int* __restrict__ ssrc,
    const short* __restrict__ sdst, const float2* __restrict__ sattr,
    float* __restrict__ agg) {
    __shared__ __align__(16) unsigned short S[64 * SH];   // overlay: A(160) then H(256)
    __shared__ short dstl[64];
    __shared__ unsigned char starts[68];
    __shared__ int nseg;

    const int base = blockIdx.x * 64, b = blockIdx.y;
    const int tid = threadIdx.x, lane = tid & 63, w = tid >> 6;
    const int m15 = lane & 15, q = lane >> 4;

    if (tid < 64) {
        int eg = base + tid;
        dstl[tid] = (eg < E_EDGES) ? sdst[eg] : (short)-1;
    }
    __syncthreads();

    if (tid == 0) {   // serial segment scan, overlaps with staging by other threads
        int ns = 0; short prev = -2; int r = 0;
        for (; r < 64; ++r) {
            short d = dstl[r];
            if (d < 0) break;
            if (d != prev) { starts[ns++] = (unsigned char)r; prev = d; }
        }
        starts[ns] = (unsigned char)r;
        nseg = ns;
    }

    // stage layer-0 input [x(78)|h3(78)|attr(2)|pad(2)] at stride SH, RTZ pack.
    // invalid rows (tail tile) read row 0 (finite) — their garbage stays row-local.
    {
        const int rr = tid >> 2, j = tid & 3;
        const int eg = base + rr;
        const int valid = dstl[rr] >= 0;
        const float* xr = x + ((size_t)b * E_EDGES + (valid ? ssrc[eg] : 0)) * FIN;
        const float* hr = h3 + (valid ? (int)dstl[rr] : 0) * FIN;
        unsigned short* Sr = S + rr * SH;
#pragma unroll
        for (int t = 0; t < 10; ++t) {
            int p = j + 4 * t;
            if (p < 39) {
                float2 f = *(const float2*)(xr + 2 * p);
                float2 g = *(const float2*)(hr + 2 * p);
                *(unsigned*)(Sr + 2 * p) = packRTZ(f.x, f.y);
                *(unsigned*)(Sr + 78 + 2 * p) = packRTZ(g.x, g.y);
            }
        }
        if (j == 3) {
            unsigned av = 0;
            if (valid) { float2 a2 = sattr[eg]; av = packRTZ(a2.x, a2.y); }
            *(unsigned*)(Sr + 156) = av;
            *(unsigned*)(Sr + 158) = 0;
        }
    }
    float bnf[4];
#pragma unroll
    for (int nf = 0; nf < 4; ++nf) bnf[nf] = eb2[w * 64 + nf * 16 + m15];
    __syncthreads();

    f32x4 acc[4][4];
    zero_acc<4>(acc);
    run_layer<4, 5>(S, SH, wpack + WOFF_E0, w * 4, m15, q, acc);   // K=160
    __syncthreads();
    epi_act<4>(S, SH, acc, eb0, w, m15, q);
    __syncthreads();

    zero_acc<4>(acc);
    run_layer<4, 8>(S, SH, wpack + WOFF_E1, w * 4, m15, q, acc);   // K=256
    __syncthreads();
    epi_act<4>(S, SH, acc, eb1, w, m15, q);
    __syncthreads();

    zero_acc<4>(acc);
    run_layer<4, 8>(S, SH, wpack + WOFF_E2, w * 4, m15, q, acc);   // K=256

    // per-nf in-register segment reduce + predicated atomic flush
    const int ns = nseg;
#pragma unroll
    for (int nf = 0; nf < 4; ++nf) {
        for (int s = 0; s < ns; ++s) {
            const int lo = starts[s], hi = starts[s + 1];
            float t = 0.f;
#pragma unroll
            for (int mf = 0; mf < 4; ++mf)
#pragma unroll
                for (int r4 = 0; r4 < 4; ++r4) {
                    int row = mf * 16 + q * 4 + r4;
                    t += (row >= lo && row < hi) ? acc[mf][nf][r4] : 0.f;
                }
            t += __shfl_xor(t, 16, 64);
            t += __shfl_xor(t, 32, 64);
            if (q == nf) {
                int dc = dstl[lo];
                atomicAdd(&agg[((size_t)b * NC + dc) * 256 + w * 64 + nf * 16 + m15],
                          t + bnf[nf] * (float)(hi - lo));
            }
        }
    }
}

// ---------------- node MLP (16-row tiles, MF=1, overlay) ----------------
__global__ __launch_bounds__(256, 4) void node_mlp_kernel(
    const float* __restrict__ h3, const float* __restrict__ agg,
    const float* __restrict__ nb0, const float* __restrict__ nb1, const float* __restrict__ nb2,
    const unsigned short* __restrict__ wpack, float* __restrict__ out) {
    __shared__ __align__(16) unsigned short S[16 * SA_N];

    const int base = blockIdx.x * 16;
    const int tid = threadIdx.x, lane = tid & 63, w = tid >> 6;
    const int m15 = lane & 15, q = lane >> 4;

    // stage [h3(78)|agg(256)|zero(18)] at stride SA_N; 16 lanes per row
    {
        const int rr = tid >> 4, l16 = tid & 15;
        const int jj = base + rr;
        const int vl = jj < NROWS_NODE;
        const int c = vl ? jj % NC : 0;
        const float* hr = h3 + c * FIN;
        const float* ar = agg + (size_t)jj * 256;
        unsigned short* Sr = S + rr * SA_N;
#pragma unroll
        for (int t = 0; t < 12; ++t) {
            int p = l16 + 16 * t;
            if (p < 39) {
                float2 f = *(const float2*)(hr + 2 * p);
                *(unsigned*)(Sr + 2 * p) = packRTZ(f.x, f.y);
            } else if (p < 167) {
                unsigned v = 0;
                if (vl) { float2 f = *(const float2*)(ar + 2 * p - 78); v = packRTZ(f.x, f.y); }
                *(unsigned*)(Sr + 2 * p) = v;
            } else if (p < 176) {
                *(unsigned*)(Sr + 2 * p) = 0;   // cols 334..351 zero (read by K=352)
            }
        }
    }
    __syncthreads();

    f32x4 acc[1][4];
    zero_acc<1>(acc);
    run_layer<1, 11>(S, SA_N, wpack + WOFF_N0, w * 4, m15, q, acc);   // K=352
    __syncthreads();
    epi_act<1>(S, SA_N, acc, nb0, w, m15, q);
    __syncthreads();

    zero_acc<1>(acc);
    run_layer<1, 8>(S, SA_N, wpack + WOFF_N1, w * 4, m15, q, acc);
    __syncthreads();
    epi_act<1>(S, SA_N, acc, nb1, w, m15, q);
    __syncthreads();

    zero_acc<1>(acc);
    run_layer<1, 8>(S, SA_N, wpack + WOFF_N2, w * 4, m15, q, acc);

#pragma unroll
    for (int nf = 0; nf < 4; ++nf) {
        int col = w * 64 + nf * 16 + m15;
        float bv = nb2[col];
#pragma unroll
        for (int r4 = 0; r4 < 4; ++r4) {
            int jj = base + q * 4 + r4;
            if (jj < NROWS_NODE) out[(size_t)jj * 256 + col] = acc[0][nf][r4] + bv;
        }
    }
}

// ---------------- tail: residual MLP (32-row tiles) + idx copy, one kernel ----------------
__global__ __launch_bounds__(256, 4) void tail_kernel(
    const float* __restrict__ la, const float* __restrict__ rb0, const float* __restrict__ rb1,
    const float* __restrict__ rb2, const float* __restrict__ rWs, const float* __restrict__ rbs,
    const unsigned short* __restrict__ wpack, const int* __restrict__ lei,
    float* __restrict__ out) {
    __shared__ __align__(16) unsigned short S[32 * SH];

    const int blk = blockIdx.x;
    const int tid = threadIdx.x;
    if (blk >= 185) {   // idx passthrough: float(latent_edge_index)
        for (int i = (blk - 185) * 256 + tid; i < OUT_IDX_N; i += 7 * 256)
            out[OUT_IDX_OFF + i] = (float)lei[i];
        return;
    }

    const int base = blk * 32;
    const int lane = tid & 63, w = tid >> 6;
    const int m15 = lane & 15, q = lane >> 4;

    {   // stage [la(2)|zero(30)] at stride SH; 8 lanes per row, 16 pairs
        const int rr = tid >> 3, j = tid & 7;
        unsigned short* Sr = S + rr * SH;
        unsigned v0 = 0;
        if (j == 0 && base + rr < E_LAT) {
            float2 f = *(const float2*)(la + (size_t)(base + rr) * 2);
            v0 = packRTZ(f.x, f.y);
        }
        *(unsigned*)(Sr + 2 * j) = v0;
        *(unsigned*)(Sr + 2 * (j + 8)) = 0;
    }
    __syncthreads();

    f32x4 acc[2][4];
    zero_acc<2>(acc);
    run_layer<2, 1>(S, SH, wpack + WOFF_R0, w * 4, m15, q, acc);   // K=32 (2 real)
    __syncthreads();
    epi_act<2>(S, SH, acc, rb0, w, m15, q);
    __syncthreads();

    zero_acc<2>(acc);
    run_layer<2, 8>(S, SH, wpack + WOFF_R1, w * 4, m15, q, acc);
    __syncthreads();
    epi_act<2>(S, SH, acc, rb1, w, m15, q);
    __syncthreads();

    zero_acc<2>(acc);
    run_layer<2, 8>(S, SH, wpack + WOFF_R2, w * 4, m15, q, acc);

    float* outA = out + OUT_ATTR_OFF;
#pragma unroll
    for (int nf = 0; nf < 4; ++nf) {
        int col = w * 64 + nf * 16 + m15;
        float bv = rb2[col] + rbs[col];
        float ws0 = rWs[col], ws1 = rWs[256 + col];
#pragma unroll
        for (int mf = 0; mf < 2; ++mf)
#pragma unroll
            for (int r4 = 0; r4 < 4; ++r4) {
                int row = mf * 16 + q * 4 + r4;
                int e = base + row;
                if (e < E_LAT) {
                    float v = acc[mf][nf][r4] + bv + la[e * 2] * ws0 + la[e * 2 + 1] * ws1;
                    outA[(size_t)e * 256 + col] = v;
                }
            }
    }
}

// ---------------- launch ----------------
extern "C" void kernel_launch(void* const* d_in, const int* in_sizes, int n_in,
                              void* d_out, int out_size, void* d_ws, size_t ws_size,
                              hipStream_t stream) {
    const float* x      = (const float*)d_in[0];
    const int*   eidx   = (const int*)d_in[1];
    const float* eattr  = (const float*)d_in[2];
    const int*   lei    = (const int*)d_in[3];
    const float* la     = (const float*)d_in[4];
    const float* h3     = (const float*)d_in[5];
    const float* eW0 = (const float*)d_in[6],  *eb0 = (const float*)d_in[7];
    const float* eW1 = (const float*)d_in[8],  *eb1 = (const float*)d_in[9];
    const float* eW2 = (const float*)d_in[10], *eb2 = (const float*)d_in[11];
    const float* nW0 = (const float*)d_in[12], *nb0 = (const float*)d_in[13];
    const float* nW1 = (const float*)d_in[14], *nb1 = (const float*)d_in[15];
    const float* nW2 = (const float*)d_in[16], *nb2 = (const float*)d_in[17];
    const float* rW0 = (const float*)d_in[18], *rb0 = (const float*)d_in[19];
    const float* rW1 = (const float*)d_in[20], *rb1 = (const float*)d_in[21];
    const float* rW2 = (const float*)d_in[22], *rb2 = (const float*)d_in[23];
    const float* rWs = (const float*)d_in[24], *rbs = (const float*)d_in[25];

    char* ws = (char*)d_ws;
    float* agg    = (float*)(ws + AGG_OFF);
    int* cnt      = (int*)(ws + CNT_OFF);
    int* cur      = (int*)(ws + CUR_OFF);
    int* ssrc     = (int*)(ws + SSRC_OFF);
    short* sdst   = (short*)(ws + SDST_OFF);
    float2* sattr = (float2*)(ws + SATTR_OFF);
    unsigned short* wpack = (unsigned short*)(ws + WPACK_OFF);

    float* out = (float*)d_out;

    hipMemsetAsync(d_ws, 0, CUR_OFF, stream);   // agg + histogram counters

    pack_weights<<<1040, 512, 0, stream>>>(eW0, eW1, eW2, nW0, nW1, nW2, rW0, rW1, rW2, wpack);
    hist_kernel<<<254, 256, 0, stream>>>(eidx + E_EDGES, cnt);
    scan_kernel<<<1, 1024, 0, stream>>>(cnt, cur);
    scatter_kernel<<<254, 256, 0, stream>>>(eidx, eidx + E_EDGES, eattr, cur,
                                            ssrc, sdst, sattr);
    tail_kernel<<<192, 256, 0, stream>>>(la, rb0, rb1, rb2, rWs, rbs, wpack, lei, out);
    edge_mlp_kernel<<<dim3(NTILES_E, NB), 256, 0, stream>>>(x, h3, eb0, eb1, eb2,
                                                            wpack, ssrc, sdst, sattr, agg);
    node_mlp_kernel<<<421, 256, 0, stream>>>(h3, agg, nb0, nb1, nb2, wpack, out);
}

// Round 5
// 693.958 us; speedup vs baseline: 1.4090x; 1.0386x over previous
//
#include <hip/hip_runtime.h>

// ---------------- problem constants ----------------
#define E_EDGES 64800
#define NC      842
#define NB      8          // b*t = 2*4
#define FIN     78
#define E_LAT   5894
#define NROWS_NODE (NB*NC)   // 6736
#define NTILES_E 2025        // 64800/32 exact

// output layout (flat float32)
#define OUT_IDX_OFF   1724416
#define OUT_IDX_N     11788
#define OUT_ATTR_OFF  1736204

// workspace layout (bytes)
#define AGG_OFF    0
#define CNT_OFF    6897664
#define CUR_OFF    6901032
#define SSRC_OFF   6904400
#define SDST_OFF   7163600
#define SATTR_OFF  7293200
#define WPACK_OFF  7811600

// packed-weight element offsets (bf16 elements)
#define WOFF_E0 0
#define WOFF_E1 40960
#define WOFF_E2 106496
#define WOFF_N0 172032
#define WOFF_N1 262144
#define WOFF_N2 327680
#define WOFF_R0 393216
#define WOFF_R1 401408
#define WOFF_R2 466944

// LDS strides (bf16 elems): dword stride ≡ 3 or 5 (mod 8) keeps b128 A-frag
// reads ≤2-way bank-aliased (free).  262 -> 131 dw (3 mod 8); 362 -> 181 dw (5 mod 8).
#define SH   262
#define SA_N 362

typedef __bf16 bf16x8 __attribute__((ext_vector_type(8)));
typedef float  f32x4  __attribute__((ext_vector_type(4)));

__device__ __forceinline__ unsigned short f2bf(float f) {   // RNE (pack_weights only)
    unsigned u = __builtin_bit_cast(unsigned, f);
    return (unsigned short)((u + 0x7fffu + ((u >> 16) & 1u)) >> 16);
}
// RTZ pack of two floats into two bf16 in one v_perm_b32
__device__ __forceinline__ unsigned packRTZ(float lo, float hi) {
    return __builtin_amdgcn_perm(__builtin_bit_cast(unsigned, hi),
                                 __builtin_bit_cast(unsigned, lo), 0x07060302u);
}

template<int MF>
__device__ __forceinline__ void zero_acc(f32x4 (&acc)[MF][4]) {
#pragma unroll
    for (int mf = 0; mf < MF; ++mf)
#pragma unroll
        for (int nf = 0; nf < 4; ++nf)
            acc[mf][nf] = (f32x4){0.f, 0.f, 0.f, 0.f};
}

// C[MF*16 rows x 64-col wave slice] += A_lds * Wpacked, B-fragment prefetch.
template<int MF, int NKS>
__device__ __forceinline__ void run_layer(const unsigned short* lA, int strideA,
                                          const unsigned short* Wp, int nfg0,
                                          int m15, int q, f32x4 (&acc)[MF][4]) {
    const unsigned short* wp0 = Wp + (size_t)nfg0 * 512 + (threadIdx.x & 63) * 8;
    bf16x8 bcur[4], bnxt[4];
#pragma unroll
    for (int nf = 0; nf < 4; ++nf) bcur[nf] = *(const bf16x8*)(wp0 + nf * 512);
#pragma unroll
    for (int kk = 0; kk < NKS; ++kk) {
        if (kk + 1 < NKS) {
#pragma unroll
            for (int nf = 0; nf < 4; ++nf)
                bnxt[nf] = *(const bf16x8*)(wp0 + (size_t)(kk + 1) * 16 * 512 + nf * 512);
        }
        bf16x8 a[MF];
#pragma unroll
        for (int mf = 0; mf < MF; ++mf)
            a[mf] = *(const bf16x8*)(lA + (mf * 16 + m15) * strideA + kk * 32 + q * 8);
#pragma unroll
        for (int nf = 0; nf < 4; ++nf)
#pragma unroll
            for (int mf = 0; mf < MF; ++mf)
                acc[mf][nf] = __builtin_amdgcn_mfma_f32_16x16x32_bf16(a[mf], bcur[nf], acc[mf][nf], 0, 0, 0);
#pragma unroll
        for (int nf = 0; nf < 4; ++nf) bcur[nf] = bnxt[nf];
    }
}

// S[row*stride+col] = bf16_rtz(leaky(acc + bias[col])); leaky = max(y, 0.01y)
template<int MF>
__device__ __forceinline__ void epi_act(unsigned short* Sb, int stride, const f32x4 (&acc)[MF][4],
                                        const float* bias, int w, int m15, int q) {
#pragma unroll
    for (int nf = 0; nf < 4; ++nf) {
        int col = w * 64 + nf * 16 + m15;
        float bv = bias[col];
#pragma unroll
        for (int mf = 0; mf < MF; ++mf)
#pragma unroll
            for (int r4 = 0; r4 < 4; ++r4) {
                int row = mf * 16 + q * 4 + r4;
                float y = acc[mf][nf][r4] + bv;
                y = fmaxf(y, 0.01f * y);
                Sb[row * stride + col] = (unsigned short)(__builtin_bit_cast(unsigned, y) >> 16);
            }
    }
}

// ---------------- weight packing ----------------
__global__ void pack_weights(const float* s0, const float* s1, const float* s2,
                             const float* s3, const float* s4, const float* s5,
                             const float* s6, const float* s7, const float* s8,
                             unsigned short* wp) {
    const int ksA[9]  = {5, 8, 8, 11, 8, 8, 1, 8, 8};
    const int kaA[9]  = {158, 256, 256, 334, 256, 256, 2, 256, 256};
    const int offA[9] = {WOFF_E0, WOFF_E1, WOFF_E2, WOFF_N0, WOFF_N1, WOFF_N2,
                         WOFF_R0, WOFF_R1, WOFF_R2};
    const float* srcs[9] = {s0, s1, s2, s3, s4, s5, s6, s7, s8};
    int rem = blockIdx.x;
    int l = 0;
    while (rem >= ksA[l] * 16) { rem -= ksA[l] * 16; ++l; }
    int kk = rem >> 4, nf = rem & 15;
    int lane = threadIdx.x >> 3, j = threadIdx.x & 7;
    int k = kk * 32 + (lane >> 4) * 8 + j;
    int n = nf * 16 + (lane & 15);
    float v = (k < kaA[l]) ? srcs[l][k * 256 + n] : 0.f;
    wp[(size_t)offA[l] + (size_t)(kk * 16 + nf) * 512 + lane * 8 + j] = f2bf(v);
}

// ---------------- counting sort of edges by dst (+ gather sorted meta) ----------------
__global__ void hist_kernel(const int* __restrict__ dstA, int* __restrict__ cnt) {
    int e = blockIdx.x * 256 + threadIdx.x;
    if (e < E_EDGES) atomicAdd(&cnt[dstA[e]], 1);
}
__global__ void scan_kernel(const int* __restrict__ cnt, int* __restrict__ cursor) {
    __shared__ int s[1024];
    int t = threadIdx.x;
    s[t] = (t < NC) ? cnt[t] : 0;
    __syncthreads();
    for (int d = 1; d < 1024; d <<= 1) {
        int v = (t >= d) ? s[t - d] : 0;
        __syncthreads();
        s[t] += v;
        __syncthreads();
    }
    if (t < NC) cursor[t] = (t == 0) ? 0 : s[t - 1];
}
__global__ void scatter_kernel(const int* __restrict__ srcA, const int* __restrict__ dstA,
                               const float* __restrict__ eattr, int* __restrict__ cursor,
                               int* __restrict__ ssrc, short* __restrict__ sdst,
                               float2* __restrict__ sattr) {
    int e = blockIdx.x * 256 + threadIdx.x;
    if (e < E_EDGES) {
        int d = dstA[e];
        int p = atomicAdd(&cursor[d], 1);
        ssrc[p] = srcA[e];
        sdst[p] = (short)d;
        sattr[p] = ((const float2*)eattr)[e];
    }
}

// ------- fused 3-layer edge MLP: 32-row tiles (MF=2), 6 blocks/CU target ----
__global__ __launch_bounds__(256, 6) void edge_mlp_kernel(
    const float* __restrict__ x, const float* __restrict__ h3,
    const float* __restrict__ eb0, const float* __restrict__ eb1, const float* __restrict__ eb2,
    const unsigned short* __restrict__ wpack, const int* __restrict__ ssrc,
    const short* __restrict__ sdst, const float2* __restrict__ sattr,
    float* __restrict__ agg) {
    __shared__ __align__(16) unsigned short S[32 * SH];   // overlay: A(160) then H(256)
    __shared__ short dstl[32];
    __shared__ unsigned char starts[36];
    __shared__ int nseg;

    const int base = blockIdx.x * 32, b = blockIdx.y;
    const int tid = threadIdx.x, lane = tid & 63, w = tid >> 6;
    const int m15 = lane & 15, q = lane >> 4;

    if (tid < 32) dstl[tid] = sdst[base + tid];
    __syncthreads();

    if (tid == 0) {   // serial segment scan (32 rows), overlaps with staging
        int ns = 0; short prev = -2;
        for (int r = 0; r < 32; ++r) {
            short d = dstl[r];
            if (d != prev) { starts[ns++] = (unsigned char)r; prev = d; }
        }
        starts[ns] = 32;
        nseg = ns;
    }

    // stage layer-0 input [x(78)|h3(78)|attr(2)|pad(2)] at stride SH, RTZ pack.
    // 8 threads per row; grid is exact (64800 = 2025*32) so no validity checks.
    {
        const int rr = tid >> 3, j = tid & 7;
        const int eg = base + rr;
        const float* xr = x + ((size_t)b * E_EDGES + ssrc[eg]) * FIN;
        const float* hr = h3 + (int)dstl[rr] * FIN;
        unsigned short* Sr = S + rr * SH;
#pragma unroll
        for (int t = 0; t < 5; ++t) {
            int p = j + 8 * t;
            if (p < 39) {
                float2 f = *(const float2*)(xr + 2 * p);
                float2 g = *(const float2*)(hr + 2 * p);
                *(unsigned*)(Sr + 2 * p) = packRTZ(f.x, f.y);
                *(unsigned*)(Sr + 78 + 2 * p) = packRTZ(g.x, g.y);
            } else if (p == 39) {
                float2 a2 = sattr[eg];
                *(unsigned*)(Sr + 156) = packRTZ(a2.x, a2.y);
                *(unsigned*)(Sr + 158) = 0;
            }
        }
    }
    float bnf[4];
#pragma unroll
    for (int nf = 0; nf < 4; ++nf) bnf[nf] = eb2[w * 64 + nf * 16 + m15];
    __syncthreads();

    f32x4 acc[2][4];
    zero_acc<2>(acc);
    run_layer<2, 5>(S, SH, wpack + WOFF_E0, w * 4, m15, q, acc);   // K=160
    __syncthreads();
    epi_act<2>(S, SH, acc, eb0, w, m15, q);
    __syncthreads();

    zero_acc<2>(acc);
    run_layer<2, 8>(S, SH, wpack + WOFF_E1, w * 4, m15, q, acc);   // K=256
    __syncthreads();
    epi_act<2>(S, SH, acc, eb1, w, m15, q);
    __syncthreads();

    zero_acc<2>(acc);
    run_layer<2, 8>(S, SH, wpack + WOFF_E2, w * 4, m15, q, acc);   // K=256

    // per-nf in-register segment reduce + predicated atomic flush
    const int ns = nseg;
#pragma unroll
    for (int nf = 0; nf < 4; ++nf) {
        for (int s = 0; s < ns; ++s) {
            const int lo = starts[s], hi = starts[s + 1];
            float t = 0.f;
#pragma unroll
            for (int mf = 0; mf < 2; ++mf)
#pragma unroll
                for (int r4 = 0; r4 < 4; ++r4) {
                    int row = mf * 16 + q * 4 + r4;
                    t += (row >= lo && row < hi) ? acc[mf][nf][r4] : 0.f;
                }
            t += __shfl_xor(t, 16, 64);
            t += __shfl_xor(t, 32, 64);
            if (q == nf) {
                int dc = dstl[lo];
                atomicAdd(&agg[((size_t)b * NC + dc) * 256 + w * 64 + nf * 16 + m15],
                          t + bnf[nf] * (float)(hi - lo));
            }
        }
    }
}

// ---------------- node MLP (16-row tiles, MF=1, overlay) ----------------
__global__ __launch_bounds__(256, 4) void node_mlp_kernel(
    const float* __restrict__ h3, const float* __restrict__ agg,
    const float* __restrict__ nb0, const float* __restrict__ nb1, const float* __restrict__ nb2,
    const unsigned short* __restrict__ wpack, float* __restrict__ out) {
    __shared__ __align__(16) unsigned short S[16 * SA_N];

    const int base = blockIdx.x * 16;
    const int tid = threadIdx.x, lane = tid & 63, w = tid >> 6;
    const int m15 = lane & 15, q = lane >> 4;

    // stage [h3(78)|agg(256)|zero(18)] at stride SA_N; 16 lanes per row
    {
        const int rr = tid >> 4, l16 = tid & 15;
        const int jj = base + rr;
        const int vl = jj < NROWS_NODE;
        const int c = vl ? jj % NC : 0;
        const float* hr = h3 + c * FIN;
        const float* ar = agg + (size_t)jj * 256;
        unsigned short* Sr = S + rr * SA_N;
#pragma unroll
        for (int t = 0; t < 12; ++t) {
            int p = l16 + 16 * t;
            if (p < 39) {
                float2 f = *(const float2*)(hr + 2 * p);
                *(unsigned*)(Sr + 2 * p) = packRTZ(f.x, f.y);
            } else if (p < 167) {
                unsigned v = 0;
                if (vl) { float2 f = *(const float2*)(ar + 2 * p - 78); v = packRTZ(f.x, f.y); }
                *(unsigned*)(Sr + 2 * p) = v;
            } else if (p < 176) {
                *(unsigned*)(Sr + 2 * p) = 0;   // cols 334..351 zero (read by K=352)
            }
        }
    }
    __syncthreads();

    f32x4 acc[1][4];
    zero_acc<1>(acc);
    run_layer<1, 11>(S, SA_N, wpack + WOFF_N0, w * 4, m15, q, acc);   // K=352
    __syncthreads();
    epi_act<1>(S, SA_N, acc, nb0, w, m15, q);
    __syncthreads();

    zero_acc<1>(acc);
    run_layer<1, 8>(S, SA_N, wpack + WOFF_N1, w * 4, m15, q, acc);
    __syncthreads();
    epi_act<1>(S, SA_N, acc, nb1, w, m15, q);
    __syncthreads();

    zero_acc<1>(acc);
    run_layer<1, 8>(S, SA_N, wpack + WOFF_N2, w * 4, m15, q, acc);

#pragma unroll
    for (int nf = 0; nf < 4; ++nf) {
        int col = w * 64 + nf * 16 + m15;
        float bv = nb2[col];
#pragma unroll
        for (int r4 = 0; r4 < 4; ++r4) {
            int jj = base + q * 4 + r4;
            if (jj < NROWS_NODE) out[(size_t)jj * 256 + col] = acc[0][nf][r4] + bv;
        }
    }
}

// ---------------- tail: residual MLP (32-row tiles) + idx copy, one kernel ----------------
__global__ __launch_bounds__(256, 4) void tail_kernel(
    const float* __restrict__ la, const float* __restrict__ rb0, const float* __restrict__ rb1,
    const float* __restrict__ rb2, const float* __restrict__ rWs, const float* __restrict__ rbs,
    const unsigned short* __restrict__ wpack, const int* __restrict__ lei,
    float* __restrict__ out) {
    __shared__ __align__(16) unsigned short S[32 * SH];

    const int blk = blockIdx.x;
    const int tid = threadIdx.x;
    if (blk >= 185) {   // idx passthrough: float(latent_edge_index)
        for (int i = (blk - 185) * 256 + tid; i < OUT_IDX_N; i += 7 * 256)
            out[OUT_IDX_OFF + i] = (float)lei[i];
        return;
    }

    const int base = blk * 32;
    const int lane = tid & 63, w = tid >> 6;
    const int m15 = lane & 15, q = lane >> 4;

    {   // stage [la(2)|zero(30)] at stride SH; 8 lanes per row, 16 pairs
        const int rr = tid >> 3, j = tid & 7;
        unsigned short* Sr = S + rr * SH;
        unsigned v0 = 0;
        if (j == 0 && base + rr < E_LAT) {
            float2 f = *(const float2*)(la + (size_t)(base + rr) * 2);
            v0 = packRTZ(f.x, f.y);
        }
        *(unsigned*)(Sr + 2 * j) = v0;
        *(unsigned*)(Sr + 2 * (j + 8)) = 0;
    }
    __syncthreads();

    f32x4 acc[2][4];
    zero_acc<2>(acc);
    run_layer<2, 1>(S, SH, wpack + WOFF_R0, w * 4, m15, q, acc);   // K=32 (2 real)
    __syncthreads();
    epi_act<2>(S, SH, acc, rb0, w, m15, q);
    __syncthreads();

    zero_acc<2>(acc);
    run_layer<2, 8>(S, SH, wpack + WOFF_R1, w * 4, m15, q, acc);
    __syncthreads();
    epi_act<2>(S, SH, acc, rb1, w, m15, q);
    __syncthreads();

    zero_acc<2>(acc);
    run_layer<2, 8>(S, SH, wpack + WOFF_R2, w * 4, m15, q, acc);

    float* outA = out + OUT_ATTR_OFF;
#pragma unroll
    for (int nf = 0; nf < 4; ++nf) {
        int col = w * 64 + nf * 16 + m15;
        float bv = rb2[col] + rbs[col];
        float ws0 = rWs[col], ws1 = rWs[256 + col];
#pragma unroll
        for (int mf = 0; mf < 2; ++mf)
#pragma unroll
            for (int r4 = 0; r4 < 4; ++r4) {
                int row = mf * 16 + q * 4 + r4;
                int e = base + row;
                if (e < E_LAT) {
                    float v = acc[mf][nf][r4] + bv + la[e * 2] * ws0 + la[e * 2 + 1] * ws1;
                    outA[(size_t)e * 256 + col] = v;
                }
            }
    }
}

// ---------------- launch ----------------
extern "C" void kernel_launch(void* const* d_in, const int* in_sizes, int n_in,
                              void* d_out, int out_size, void* d_ws, size_t ws_size,
                              hipStream_t stream) {
    const float* x      = (const float*)d_in[0];
    const int*   eidx   = (const int*)d_in[1];
    const float* eattr  = (const float*)d_in[2];
    const int*   lei    = (const int*)d_in[3];
    const float* la     = (const float*)d_in[4];
    const float* h3     = (const float*)d_in[5];
    const float* eW0 = (const float*)d_in[6],  *eb0 = (const float*)d_in[7];
    const float* eW1 = (const float*)d_in[8],  *eb1 = (const float*)d_in[9];
    const float* eW2 = (const float*)d_in[10], *eb2 = (const float*)d_in[11];
    const float* nW0 = (const float*)d_in[12], *nb0 = (const float*)d_in[13];
    const float* nW1 = (const float*)d_in[14], *nb1 = (const float*)d_in[15];
    const float* nW2 = (const float*)d_in[16], *nb2 = (const float*)d_in[17];
    const float* rW0 = (const float*)d_in[18], *rb0 = (const float*)d_in[19];
    const float* rW1 = (const float*)d_in[20], *rb1 = (const float*)d_in[21];
    const float* rW2 = (const float*)d_in[22], *rb2 = (const float*)d_in[23];
    const float* rWs = (const float*)d_in[24], *rbs = (const float*)d_in[25];

    char* ws = (char*)d_ws;
    float* agg    = (float*)(ws + AGG_OFF);
    int* cnt      = (int*)(ws + CNT_OFF);
    int* cur      = (int*)(ws + CUR_OFF);
    int* ssrc     = (int*)(ws + SSRC_OFF);
    short* sdst   = (short*)(ws + SDST_OFF);
    float2* sattr = (float2*)(ws + SATTR_OFF);
    unsigned short* wpack = (unsigned short*)(ws + WPACK_OFF);

    float* out = (float*)d_out;

    hipMemsetAsync(d_ws, 0, CUR_OFF, stream);   // agg + histogram counters

    pack_weights<<<1040, 512, 0, stream>>>(eW0, eW1, eW2, nW0, nW1, nW2, rW0, rW1, rW2, wpack);
    hist_kernel<<<254, 256, 0, stream>>>(eidx + E_EDGES, cnt);
    scan_kernel<<<1, 1024, 0, stream>>>(cnt, cur);
    scatter_kernel<<<254, 256, 0, stream>>>(eidx, eidx + E_EDGES, eattr, cur,
                                            ssrc, sdst, sattr);
    tail_kernel<<<192, 256, 0, stream>>>(la, rb0, rb1, rb2, rWs, rbs, wpack, lei, out);
    edge_mlp_kernel<<<dim3(NTILES_E, NB), 256, 0, stream>>>(x, h3, eb0, eb1, eb2,
                                                            wpack, ssrc, sdst, sattr, agg);
    node_mlp_kernel<<<421, 256, 0, stream>>>(h3, agg, nb0, nb1, nb2, wpack, out);
}